// Round 7
// baseline (166.020 us; speedup 1.0000x reference)
//
#include <hip/hip_runtime.h>
#include <hip/hip_bf16.h>

#define N_NODES 8192
#define E_EDGES 16384
#define S_SEG   16
#define EXT     64
#define P_PATHS 2048
#define ROW     1024            // S_SEG*EXT floats per row
#define L_SLOTS 8               // edge slots per wave
#define NWAVES  (E_EDGES / L_SLOTS)   // 2048
#define NBLK    (NWAVES / 4)          // 512 blocks x 4 waves -> all resident

typedef _Float16 f16x8  __attribute__((ext_vector_type(8)));
typedef _Float16 half2v __attribute__((ext_vector_type(2)));
typedef float    f32x4  __attribute__((ext_vector_type(4)));

#define PKRTZ(a, b) __builtin_bit_cast(half2v, __builtin_amdgcn_cvt_pkrtz((a), (b)))

// async global->LDS DMA, 16B per lane, lands at lds_base + lane*16
#define GLOAD16(gp, lp)                                                  \
    __builtin_amdgcn_global_load_lds(                                    \
        (const __attribute__((address_space(1))) void*)(gp),             \
        (__attribute__((address_space(3))) void*)(lp), 16, 0, 0)

#define WAIT_VMCNT(n) asm volatile("s_waitcnt vmcnt(" #n ")" ::: "memory")

// ---- workspace layout (bytes) ----
#define WS_CMAT  0        // f16[4096]   8 KB
#define WS_HIST  8192     // int[8192]
#define WS_CURS  40960    // int[8192]
#define WS_ROWS  73728    // int[8193]
#define WS_ELIST 106512   // int[16384]
#define WS_XRS   172048   // int[16384]
#define WS_NDS   237584   // int[16384]

// ---------------------------------------------------------------------------
__global__ void prep(const int* __restrict__ pidx, const float* __restrict__ pcoef,
                     _Float16* __restrict__ Cmat, int* __restrict__ hist) {
    const int tid = threadIdx.x;
    if (blockIdx.x < 32) { hist[blockIdx.x * 256 + tid] = 0; return; }
    __shared__ float sC[S_SEG * S_SEG * S_SEG];
    for (int i = tid; i < 4096; i += 256) sC[i] = 0.f;
    __syncthreads();
    for (int p = tid; p < P_PATHS; p += 256) {
        int i = pidx[3 * p + 0];
        int j = pidx[3 * p + 1];
        int k = pidx[3 * p + 2];
        atomicAdd(&sC[(k * S_SEG + i) * S_SEG + j], pcoef[p]);
    }
    __syncthreads();
    for (int i = tid; i < 4096; i += 256) Cmat[i] = (_Float16)sC[i];
}

__global__ void hist_k(const int* __restrict__ idx_out, int* __restrict__ hist) {
    const int e = blockIdx.x * 256 + threadIdx.x;
    atomicAdd(&hist[idx_out[e]], 1);
}

__global__ __launch_bounds__(256) void scan_k(const int* __restrict__ hist,
                                              int* __restrict__ rows,
                                              int* __restrict__ cursor) {
    __shared__ int part[256];
    const int t = threadIdx.x;
    const int base = t * 32;
    int loc[32];
    int s = 0;
#pragma unroll
    for (int i = 0; i < 32; ++i) { loc[i] = s; s += hist[base + i]; }
    part[t] = s;
    __syncthreads();
    for (int off = 1; off < 256; off <<= 1) {
        int v = part[t];
        int u = (t >= off) ? part[t - off] : 0;
        __syncthreads();
        part[t] = v + u;
        __syncthreads();
    }
    const int excl = (t == 0) ? 0 : part[t - 1];
#pragma unroll
    for (int i = 0; i < 32; ++i) {
        int v = excl + loc[i];
        rows[base + i] = v;
        cursor[base + i] = v;
    }
    if (t == 255) rows[N_NODES] = part[255];
}

__global__ void scatter_k(const int* __restrict__ idx_in, const int* __restrict__ idx_out,
                          int* __restrict__ cursor, int* __restrict__ elist,
                          int* __restrict__ xrs, int* __restrict__ nds) {
    const int e = blockIdx.x * 256 + threadIdx.x;
    const int nd = idx_out[e];
    const int pos = atomicAdd(&cursor[nd], 1);
    elist[pos] = e;
    xrs[pos]   = idx_in[e];
    nds[pos]   = nd;
}

// zero tiles of deg-0 nodes and nodes whose slot range crosses a wave boundary
__global__ __launch_bounds__(256) void zerofill_k(const int* __restrict__ rows,
                                                  float* __restrict__ out) {
    const int n = blockIdx.x * 4 + (threadIdx.x >> 6);
    const int lane = threadIdx.x & 63;
    const int beg = rows[n], end = rows[n + 1];
    const bool need = (beg == end) || ((beg / L_SLOTS) != ((end - 1) / L_SLOTS));
    if (!need) return;
    const f32x4 z = {0.f, 0.f, 0.f, 0.f};
    float* ob = out + (size_t)n * ROW + lane * 4;
#pragma unroll
    for (int r = 0; r < 4; ++r)
        __builtin_nontemporal_store(z, (f32x4*)(ob + r * 256));
}

// ---------------------------------------------------------------------------
// main: one wave per 8 sorted edge slots. Async DMA (global_load_lds, 16B)
// stages raw fp32 x/y rows into a per-wave LDS double buffer; explicit
// s_waitcnt vmcnt(8) keeps the next edge's batch in flight during compute.
// B-fragments built from fp32 LDS reads: exact fp32 product + 1 RTZ rounding.
// ---------------------------------------------------------------------------
__global__ __launch_bounds__(256) void seg_poly_async(
        const float* __restrict__ x, const float* __restrict__ y,
        const _Float16* __restrict__ Cmat,
        const int* __restrict__ elist, const int* __restrict__ xrs,
        const int* __restrict__ nds, float* __restrict__ out) {
    // per-wave: [2 buffers][x 1024 | y 1024 floats] = 16 KB; 64 KB/block
    __shared__ __attribute__((aligned(16))) float sbuf[4][2][2048];

    const int tid  = threadIdx.x;
    const int lane = tid & 63;
    const int wv   = tid >> 6;

    const int wid = blockIdx.x * 4 + wv;     // 0..2047
    const int s0  = wid * L_SLOTS;

    const int quad = lane >> 4;     // 0..3
    const int m    = lane & 15;
    const int ih   = quad >> 1;      // x-row parity within K-step
    const int jb   = (quad & 1) * 8; // y-row base

    // per-slot metadata (wave-uniform)
    int e_[L_SLOTS], xr_[L_SLOTS], nd_[L_SLOTS];
    {
        int4 a = *(const int4*)(elist + s0); int4 b = *(const int4*)(elist + s0 + 4);
        e_[0]=a.x; e_[1]=a.y; e_[2]=a.z; e_[3]=a.w; e_[4]=b.x; e_[5]=b.y; e_[6]=b.z; e_[7]=b.w;
        a = *(const int4*)(xrs + s0); b = *(const int4*)(xrs + s0 + 4);
        xr_[0]=a.x; xr_[1]=a.y; xr_[2]=a.z; xr_[3]=a.w; xr_[4]=b.x; xr_[5]=b.y; xr_[6]=b.z; xr_[7]=b.w;
        a = *(const int4*)(nds + s0); b = *(const int4*)(nds + s0 + 4);
        nd_[0]=a.x; nd_[1]=a.y; nd_[2]=a.z; nd_[3]=a.w; nd_[4]=b.x; nd_[5]=b.y; nd_[6]=b.z; nd_[7]=b.w;
    }
    const bool prev_same = (s0 > 0)                 && (nds[s0 - 1]       == nd_[0]);
    const bool next_same = (s0 + L_SLOTS < E_EDGES) && (nds[s0 + L_SLOTS] == nd_[L_SLOTS - 1]);

    // A fragments (constant): afrag[kk][jr] = Cmat[m][kk*32 + quad*8 + jr]
    f16x8 afrag[8];
    {
        const _Float16* basep = Cmat + m * 256 + quad * 8;
#pragma unroll
        for (int kk = 0; kk < 8; ++kk) afrag[kk] = *(const f16x8*)(basep + kk * 32);
    }

    // async stage of edge t into buffer b: x -> [0..1023], y -> [1024..2047]
    auto issue = [&](int t, int b) {
        const float* xp = x + (size_t)xr_[t] * ROW;
        const float* yp = y + (size_t)e_[t] * ROW;
        float* lx = &sbuf[wv][b][0];
        float* ly = &sbuf[wv][b][1024];
#pragma unroll
        for (int k4 = 0; k4 < 4; ++k4) {
            GLOAD16(xp + k4 * 256 + lane * 4, lx + k4 * 256);
            GLOAD16(yp + k4 * 256 + lane * 4, ly + k4 * 256);
        }
    };
    issue(0, 0);
    issue(1, 1);

    f32x4 acc[4];
#pragma unroll
    for (int ct = 0; ct < 4; ++ct) acc[ct] = f32x4{0.f, 0.f, 0.f, 0.f};
    int segStart = 0;

#pragma unroll
    for (int t = 0; t < L_SLOTS; ++t) {
        const int b = t & 1;
        // wait for edge t's 8 DMAs; leave edge t+1's 8 in flight
        if (t + 1 < L_SLOTS) { WAIT_VMCNT(8); } else { WAIT_VMCNT(0); }

        const float* sX = &sbuf[wv][b][0];
        const float* sY = &sbuf[wv][b][1024];

#pragma unroll
        for (int ct = 0; ct < 4; ++ct) {
            const int c = ct * 16 + m;
            float y0[4], y1[4];
#pragma unroll
            for (int r = 0; r < 4; ++r) {
                y0[r] = sY[(jb + 2 * r) * 64 + c];
                y1[r] = sY[(jb + 2 * r + 1) * 64 + c];
            }
#pragma unroll
            for (int kk = 0; kk < 8; ++kk) {
                const float xf = sX[(2 * kk + ih) * 64 + c];
                const half2v h0 = PKRTZ(xf * y0[0], xf * y1[0]);
                const half2v h1 = PKRTZ(xf * y0[1], xf * y1[1]);
                const half2v h2 = PKRTZ(xf * y0[2], xf * y1[2]);
                const half2v h3 = PKRTZ(xf * y0[3], xf * y1[3]);
                const f16x8 bfrag = {h0[0], h0[1], h1[0], h1[1],
                                     h2[0], h2[1], h3[0], h3[1]};
                acc[ct] = __builtin_amdgcn_mfma_f32_16x16x32_f16(
                              afrag[kk], bfrag, acc[ct], 0, 0, 0);
            }
        }

        // flush at node boundary
        const bool last = (t == L_SLOTS - 1);
        if (last || nd_[t + 1] != nd_[t]) {
            const bool shared = (segStart == 0 && prev_same) || (last && next_same);
            float* ob = out + (size_t)nd_[t] * ROW;
            if (shared) {
#pragma unroll
                for (int ct = 0; ct < 4; ++ct)
#pragma unroll
                    for (int r = 0; r < 4; ++r)
                        atomicAdd(ob + (quad * 4 + r) * EXT + ct * 16 + m, acc[ct][r]);
            } else {
#pragma unroll
                for (int ct = 0; ct < 4; ++ct)
#pragma unroll
                    for (int r = 0; r < 4; ++r)
                        __builtin_nontemporal_store(
                            acc[ct][r], ob + (quad * 4 + r) * EXT + ct * 16 + m);
            }
#pragma unroll
            for (int ct = 0; ct < 4; ++ct) acc[ct] = f32x4{0.f, 0.f, 0.f, 0.f};
            segStart = t + 1;
        }

        // refill the buffer edge t just vacated (DMA data arrives >=600cyc
        // after issue; t's ds_reads are long completed by then)
        if (t + 2 < L_SLOTS) issue(t + 2, b);
    }
}

extern "C" void kernel_launch(void* const* d_in, const int* in_sizes, int n_in,
                              void* d_out, int out_size, void* d_ws, size_t ws_size,
                              hipStream_t stream) {
    const float* x       = (const float*)d_in[0];
    const float* y       = (const float*)d_in[1];
    const int*   idx_in  = (const int*)d_in[2];
    const int*   idx_out = (const int*)d_in[3];
    const int*   pidx    = (const int*)d_in[4];
    const float* pcoef   = (const float*)d_in[5];
    float* out           = (float*)d_out;

    char* ws = (char*)d_ws;
    _Float16* Cmat = (_Float16*)(ws + WS_CMAT);
    int* hist      = (int*)(ws + WS_HIST);
    int* cursor    = (int*)(ws + WS_CURS);
    int* rows      = (int*)(ws + WS_ROWS);
    int* elist     = (int*)(ws + WS_ELIST);
    int* xrs       = (int*)(ws + WS_XRS);
    int* nds       = (int*)(ws + WS_NDS);

    prep<<<33, 256, 0, stream>>>(pidx, pcoef, Cmat, hist);
    hist_k<<<E_EDGES / 256, 256, 0, stream>>>(idx_out, hist);
    scan_k<<<1, 256, 0, stream>>>(hist, rows, cursor);
    scatter_k<<<E_EDGES / 256, 256, 0, stream>>>(idx_in, idx_out, cursor, elist, xrs, nds);
    zerofill_k<<<N_NODES / 4, 256, 0, stream>>>(rows, out);
    seg_poly_async<<<NBLK, 256, 0, stream>>>(x, y, Cmat, elist, xrs, nds, out);
}